// Round 2
// baseline (886.388 us; speedup 1.0000x reference)
//
#include <hip/hip_runtime.h>
#include <cstdint>
#include <cstddef>

typedef __bf16 bf16x8 __attribute__((ext_vector_type(8)));
typedef float f32x4 __attribute__((ext_vector_type(4)));

union V16 { uint4 u; bf16x8 b; unsigned short s[8]; };

__device__ __forceinline__ float b2f(unsigned short u) {
  unsigned int x = ((unsigned int)u) << 16;
  float f;
  __builtin_memcpy(&f, &x, 4);
  return f;
}
__device__ __forceinline__ unsigned short f2b(float f) {
  unsigned int u;
  __builtin_memcpy(&u, &f, 4);
  u = u + 0x7FFFu + ((u >> 16) & 1u);
  return (unsigned short)(u >> 16);
}

__device__ __forceinline__ f32x4 mfma16(bf16x8 a, bf16x8 b, f32x4 c) {
  return __builtin_amdgcn_mfma_f32_16x16x32_bf16(a, b, c, 0, 0, 0);
}

// async global->LDS, 16B per lane; LDS dest is wave-uniform base (+lane*16 implicit)
__device__ __forceinline__ void gld_lds16(const unsigned short* g, unsigned short* l) {
  __builtin_amdgcn_global_load_lds((__attribute__((address_space(1))) void*)g,
                                   (__attribute__((address_space(3))) void*)l,
                                   16, 0, 0);
}

// ---------------- f32 -> bf16 convert ----------------
__global__ __launch_bounds__(256) void cvt_k(const float* __restrict__ in,
                                             unsigned short* __restrict__ out, int n) {
  const int i = (blockIdx.x * 256 + threadIdx.x) * 4;
  if (i + 3 < n) {
    const float4 v = *(const float4*)(in + i);
    ushort4 o;
    o.x = f2b(v.x); o.y = f2b(v.y); o.z = f2b(v.z); o.w = f2b(v.w);
    *(ushort4*)(out + i) = o;
  }
}

// ---------------- RMSNorm (f32 in -> bf16 out) ----------------
__global__ __launch_bounds__(256) void rms_k(const float* __restrict__ xin,
                                             const float* __restrict__ wgt,
                                             unsigned short* __restrict__ out) {
  const int s = blockIdx.x;
  const int t = threadIdx.x;
  float vals[8];
  float ss = 0.f;
#pragma unroll
  for (int i = 0; i < 8; ++i) {
    const int c = t + i * 256;
    const float f = xin[(size_t)s * 2048 + c];
    vals[i] = f;
    ss += f * f;
  }
#pragma unroll
  for (int off = 32; off > 0; off >>= 1) ss += __shfl_xor(ss, off);
  __shared__ float red[4];
  if ((t & 63) == 0) red[t >> 6] = ss;
  __syncthreads();
  ss = red[0] + red[1] + red[2] + red[3];
  const float sc = rsqrtf(ss * (1.f / 2048.f) + 1e-6f);
#pragma unroll
  for (int i = 0; i < 8; ++i) {
    const int c = t + i * 256;
    out[(size_t)s * 2048 + c] = f2b(vals[i] * sc * wgt[c]);
  }
}

// ---------------- RoPE (in-place on bf16 q and k; f32 cos/sin) ----------------
__global__ __launch_bounds__(256) void rope_qk(unsigned short* qb, unsigned short* kb,
                                               const float* __restrict__ cosb,
                                               const float* __restrict__ sinb) {
  const int idx = blockIdx.x * 256 + threadIdx.x;  // 0 .. S*H*64
  const int d = idx & 63;
  const int h = (idx >> 6) & 15;
  const int s = idx >> 10;
  const size_t base = (size_t)s * 2048 + h * 128;
  const int cb = s * 128;
  const float c1 = cosb[cb + d],      s1 = sinb[cb + d];
  const float c2 = cosb[cb + d + 64], s2 = sinb[cb + d + 64];
  {
    const float x1 = b2f(qb[base + d]), x2 = b2f(qb[base + d + 64]);
    qb[base + d]      = f2b(x1 * c1 - x2 * s1);
    qb[base + d + 64] = f2b(x2 * c2 + x1 * s2);
  }
  {
    const float x1 = b2f(kb[base + d]), x2 = b2f(kb[base + d + 64]);
    kb[base + d]      = f2b(x1 * c1 - x2 * s1);
    kb[base + d + 64] = f2b(x2 * c2 + x1 * s2);
  }
}

// ---------------- NT GEMM: C[M,N] = A[M,K] @ B[N,K]^T (bf16 in, f32 acc) ----------------
// EPI 0: C=bf16(acc)   1: Cf=auxf+acc (f32 store)   2: C=bf16(silu(auxb)*acc)
// RT=4 -> 128x128 tile, RT=2 -> 64x128 tile. gridDim.z selects B/C (QKV fusion).
template <int EPI, int RT>
__global__ __launch_bounds__(256, 2) void gemm_nt(
    const unsigned short* __restrict__ A,
    const unsigned short* __restrict__ B0,
    const unsigned short* __restrict__ B1,
    const unsigned short* __restrict__ B2,
    unsigned short* C0, unsigned short* C1, unsigned short* C2,
    const unsigned short* auxb, const float* auxf, float* Cf,
    int N, int K) {
  constexpr int TM = RT * 32;
  constexpr int APASS = TM / 64;
  const unsigned short* B = (blockIdx.z == 0) ? B0 : (blockIdx.z == 1 ? B1 : B2);
  unsigned short* C = (blockIdx.z == 0) ? C0 : (blockIdx.z == 1 ? C1 : C2);

  const int m0 = blockIdx.y * TM;
  const int n0 = blockIdx.x * 128;
  const int t = threadIdx.x;
  const int lane = t & 63;
  const int w = t >> 6;
  const int quad = lane >> 4;
  const int l15 = lane & 15;
  const int wr = w >> 1;
  const int wc = w & 1;

  __shared__ __align__(16) unsigned short As[TM * 32];
  __shared__ __align__(16) unsigned short Bs[128 * 32];

  const f32x4 vzero = {0.f, 0.f, 0.f, 0.f};
  f32x4 acc[RT][4];
#pragma unroll
  for (int i = 0; i < RT; ++i)
#pragma unroll
    for (int j = 0; j < 4; ++j) acc[i][j] = vzero;

  const int srow = w * 16 + (lane >> 2);
  const int scol = (lane & 3) * 8;
  const unsigned short* Ag = A + (size_t)(m0 + srow) * K + scol;
  const unsigned short* Bg = B + (size_t)(n0 + srow) * K + scol;

  for (int k0 = 0; k0 < K; k0 += 32) {
#pragma unroll
    for (int p = 0; p < APASS; ++p)
      gld_lds16(Ag + (size_t)p * 64 * K + k0, As + p * 2048 + w * 512);
#pragma unroll
    for (int p = 0; p < 2; ++p)
      gld_lds16(Bg + (size_t)p * 64 * K + k0, Bs + p * 2048 + w * 512);
    __syncthreads();

    bf16x8 af[RT], bfr[4];
#pragma unroll
    for (int rt = 0; rt < RT; ++rt)
      af[rt] = *(const bf16x8*)&As[(wr * (RT * 16) + rt * 16 + l15) * 32 + quad * 8];
#pragma unroll
    for (int ct = 0; ct < 4; ++ct)
      bfr[ct] = *(const bf16x8*)&Bs[(wc * 64 + ct * 16 + l15) * 32 + quad * 8];
#pragma unroll
    for (int rt = 0; rt < RT; ++rt)
#pragma unroll
      for (int ct = 0; ct < 4; ++ct)
        acc[rt][ct] = mfma16(af[rt], bfr[ct], acc[rt][ct]);
    __syncthreads();
  }

#pragma unroll
  for (int rt = 0; rt < RT; ++rt) {
#pragma unroll
    for (int ct = 0; ct < 4; ++ct) {
#pragma unroll
      for (int r = 0; r < 4; ++r) {
        const int m = m0 + wr * (RT * 16) + rt * 16 + quad * 4 + r;
        const int n = n0 + wc * 64 + ct * 16 + l15;
        const size_t idx = (size_t)m * N + n;
        const float a = acc[rt][ct][r];
        if constexpr (EPI == 0) {
          C[idx] = f2b(a);
        } else if constexpr (EPI == 1) {
          Cf[idx] = auxf[idx] + a;
        } else {
          const float g = b2f(auxb[idx]);
          const float sg = g / (1.f + __expf(-g));
          C[idx] = f2b(sg * a);
        }
      }
    }
  }
}

// ---------------- Flash W2 (Gaussian-kernel) attention ----------------
// grid (S/64, H), 256 threads. Wave w handles q rows [i0+16w, i0+16w+16).
__global__ __launch_bounds__(256, 2) void flash_w2(
    const unsigned short* __restrict__ q,
    const unsigned short* __restrict__ kk,
    const unsigned short* __restrict__ v,
    unsigned short* __restrict__ ctx) {
  constexpr int Cw = 2048;
  constexpr float inv2sd = 0.04419417382415922f;  // 1/(2*sqrt(128))
  const int h = blockIdx.y;
  const int i0 = blockIdx.x * 64;
  const int t = threadIdx.x;
  const int lane = t & 63;
  const int w = t >> 6;
  const int quad = lane >> 4;
  const int l15 = lane & 15;

  __shared__ __align__(16) unsigned short Ks[64 * 136];   // [j][d], pitch 136
  __shared__ __align__(16) unsigned short VTs[128 * 72];  // [d][j], pitch 72
  __shared__ __align__(16) unsigned short Ps[4][16 * 72]; // per-wave P, pitch 72

  // Q fragments (A-layout: row=l15, k=quad*8+j) + q^2 per row
  bf16x8 aq[4];
  float q2p = 0.f;
  {
    const unsigned short* qp = q + (size_t)(i0 + w * 16 + l15) * Cw + h * 128;
#pragma unroll
    for (int kt = 0; kt < 4; ++kt) {
      V16 u;
      u.u = *(const uint4*)(qp + kt * 32 + quad * 8);
      aq[kt] = u.b;
#pragma unroll
      for (int j = 0; j < 8; ++j) { const float f = (float)u.b[j]; q2p += f * f; }
    }
  }
  q2p += __shfl_xor(q2p, 16);
  q2p += __shfl_xor(q2p, 32);
  float q2r[4];
#pragma unroll
  for (int r = 0; r < 4; ++r) q2r[r] = __shfl(q2p, quad * 4 + r);

  const f32x4 vzero = {0.f, 0.f, 0.f, 0.f};
  f32x4 o[8];
#pragma unroll
  for (int nt = 0; nt < 8; ++nt) o[nt] = vzero;
  float mrow[4] = {-1e30f, -1e30f, -1e30f, -1e30f};
  float lrow[4] = {0.f, 0.f, 0.f, 0.f};

  const int njt = blockIdx.x + 1;
  for (int jt = 0; jt < njt; ++jt) {
    const int j0 = jt * 64;
    __syncthreads();
    {  // stage K tile and V^T tile
      const int jr = t >> 2;
      const int c0 = (t & 3) * 32;
      const unsigned short* kp = kk + (size_t)(j0 + jr) * Cw + h * 128 + c0;
      const unsigned short* vp = v + (size_t)(j0 + jr) * Cw + h * 128 + c0;
#pragma unroll
      for (int i = 0; i < 4; ++i) {
        *(uint4*)&Ks[jr * 136 + c0 + i * 8] = *(const uint4*)(kp + i * 8);
        V16 vu;
        vu.u = *(const uint4*)(vp + i * 8);
#pragma unroll
        for (int e = 0; e < 8; ++e) VTs[(c0 + i * 8 + e) * 72 + jr] = vu.s[e];
      }
    }
    __syncthreads();

    // S = Q K^T (16x64 per wave) and k^2 per column
    f32x4 sc[4];
    float k2[4];
#pragma unroll
    for (int ct = 0; ct < 4; ++ct) {
      f32x4 a = vzero;
      float k2p = 0.f;
#pragma unroll
      for (int kt = 0; kt < 4; ++kt) {
        V16 u;
        u.u = *(const uint4*)&Ks[(ct * 16 + l15) * 136 + kt * 32 + quad * 8];
        a = mfma16(aq[kt], u.b, a);
#pragma unroll
        for (int j = 0; j < 8; ++j) { const float f = (float)u.b[j]; k2p += f * f; }
      }
      k2p += __shfl_xor(k2p, 16);
      k2p += __shfl_xor(k2p, 32);
      sc[ct] = a;
      k2[ct] = k2p;
    }

    // scores + causal mask
#pragma unroll
    for (int ct = 0; ct < 4; ++ct) {
#pragma unroll
      for (int r = 0; r < 4; ++r) {
        const int gi = i0 + w * 16 + quad * 4 + r;
        const int gj = j0 + ct * 16 + l15;
        const float s = -(q2r[r] - 2.f * sc[ct][r] + k2[ct]) * inv2sd;
        sc[ct][r] = (gj <= gi) ? s : -1e30f;
      }
    }

    // online softmax (rows live in 16-lane quad groups x 4 regs)
    float al[4];
#pragma unroll
    for (int r = 0; r < 4; ++r) {
      float rm = fmaxf(fmaxf(sc[0][r], sc[1][r]), fmaxf(sc[2][r], sc[3][r]));
      rm = fmaxf(rm, __shfl_xor(rm, 1));
      rm = fmaxf(rm, __shfl_xor(rm, 2));
      rm = fmaxf(rm, __shfl_xor(rm, 4));
      rm = fmaxf(rm, __shfl_xor(rm, 8));
      const float mn = fmaxf(mrow[r], rm);
      al[r] = __expf(mrow[r] - mn);
      mrow[r] = mn;
      float ps = 0.f;
#pragma unroll
      for (int ct = 0; ct < 4; ++ct) {
        const float p = __expf(sc[ct][r] - mn);
        sc[ct][r] = p;
        ps += p;
      }
      ps += __shfl_xor(ps, 1);
      ps += __shfl_xor(ps, 2);
      ps += __shfl_xor(ps, 4);
      ps += __shfl_xor(ps, 8);
      lrow[r] = lrow[r] * al[r] + ps;
    }
#pragma unroll
    for (int nt = 0; nt < 8; ++nt)
#pragma unroll
      for (int r = 0; r < 4; ++r) o[nt][r] *= al[r];

    // P -> LDS (C-layout write, A-layout read)
#pragma unroll
    for (int ct = 0; ct < 4; ++ct)
#pragma unroll
      for (int r = 0; r < 4; ++r)
        Ps[w][(quad * 4 + r) * 72 + ct * 16 + l15] = f2b(sc[ct][r]);
    __syncthreads();

    // O += P V
#pragma unroll
    for (int kt2 = 0; kt2 < 2; ++kt2) {
      V16 pa;
      pa.u = *(const uint4*)&Ps[w][l15 * 72 + kt2 * 32 + quad * 8];
#pragma unroll
      for (int nt = 0; nt < 8; ++nt) {
        V16 vb;
        vb.u = *(const uint4*)&VTs[(nt * 16 + l15) * 72 + kt2 * 32 + quad * 8];
        o[nt] = mfma16(pa.b, vb.b, o[nt]);
      }
    }
  }

  float invl[4];
#pragma unroll
  for (int r = 0; r < 4; ++r) invl[r] = 1.f / lrow[r];
#pragma unroll
  for (int nt = 0; nt < 8; ++nt) {
#pragma unroll
    for (int r = 0; r < 4; ++r) {
      const int gi = i0 + w * 16 + quad * 4 + r;
      ctx[(size_t)gi * Cw + h * 128 + nt * 16 + l15] = f2b(o[nt][r] * invl[r]);
    }
  }
}

// ---------------- driver ----------------
extern "C" void kernel_launch(void* const* d_in, const int* in_sizes, int n_in,
                              void* d_out, int out_size, void* d_ws, size_t ws_size,
                              hipStream_t stream) {
  (void)in_sizes; (void)n_in; (void)out_size; (void)ws_size;
  const float* hid  = (const float*)d_in[0];
  const float* cosb = (const float*)d_in[1];
  const float* sinb = (const float*)d_in[2];
  // d_in[3] attention_mask: exactly causal -> applied analytically
  const float* ln1w = (const float*)d_in[4];
  const float* wq   = (const float*)d_in[5];
  const float* wk   = (const float*)d_in[6];
  const float* wv   = (const float*)d_in[7];
  const float* wo   = (const float*)d_in[8];
  const float* ln2w = (const float*)d_in[9];
  const float* wg   = (const float*)d_in[10];
  const float* wu   = (const float*)d_in[11];
  const float* wd   = (const float*)d_in[12];
  float* outp = (float*)d_out;

  const size_t SC = (size_t)2048 * 2048;       // 4.19M
  const size_t FC = (size_t)8192 * 2048;       // 16.78M
  unsigned short* p = (unsigned short*)d_ws;
  unsigned short* wqb = p;  p += SC;
  unsigned short* wkb = p;  p += SC;
  unsigned short* wvb = p;  p += SC;
  unsigned short* wob = p;  p += SC;
  unsigned short* wgb = p;  p += FC;
  unsigned short* wub = p;  p += FC;
  unsigned short* wdb = p;  p += FC;
  unsigned short* xn  = p;  p += SC;           // also reused as yn
  unsigned short* qb  = p;  p += SC;
  unsigned short* kb  = p;  p += SC;
  unsigned short* vb  = p;  p += SC;
  unsigned short* ctxb = p; p += SC;
  float* hf = (float*)p;                        // f32 h = hidden + attn_out
  unsigned short* yn = xn;                      // xn dead after QKV
  unsigned short* gb = qb;                      // qb..ctxb (4*SC == FC) dead after wo-proj

  // 0. weights f32 -> bf16
  cvt_k<<<(int)(SC / 1024), 256, 0, stream>>>(wq, wqb, (int)SC);
  cvt_k<<<(int)(SC / 1024), 256, 0, stream>>>(wk, wkb, (int)SC);
  cvt_k<<<(int)(SC / 1024), 256, 0, stream>>>(wv, wvb, (int)SC);
  cvt_k<<<(int)(SC / 1024), 256, 0, stream>>>(wo, wob, (int)SC);
  cvt_k<<<(int)(FC / 1024), 256, 0, stream>>>(wg, wgb, (int)FC);
  cvt_k<<<(int)(FC / 1024), 256, 0, stream>>>(wu, wub, (int)FC);
  cvt_k<<<(int)(FC / 1024), 256, 0, stream>>>(wd, wdb, (int)FC);

  // 1. input RMSNorm
  rms_k<<<2048, 256, 0, stream>>>(hid, ln1w, xn);
  // 2. fused QKV projection (gridDim.z selects weight/output)
  gemm_nt<0, 4><<<dim3(16, 16, 3), 256, 0, stream>>>(xn, wqb, wkb, wvb, qb, kb, vb,
                                                     nullptr, nullptr, nullptr, 2048, 2048);
  // 3. RoPE in-place on q,k
  rope_qk<<<8192, 256, 0, stream>>>(qb, kb, cosb, sinb);
  // 4. W2 attention -> ctx
  flash_w2<<<dim3(32, 16), 256, 0, stream>>>(qb, kb, vb, ctxb);
  // 5. output projection + residual -> h (f32)
  gemm_nt<1, 2><<<dim3(16, 32, 1), 256, 0, stream>>>(ctxb, wob, wob, wob,
                                                     nullptr, nullptr, nullptr,
                                                     nullptr, hid, hf, 2048, 2048);
  // 6. post-attn RMSNorm
  rms_k<<<2048, 256, 0, stream>>>(hf, ln2w, yn);
  // 7. gate GEMM
  gemm_nt<0, 4><<<dim3(64, 16, 1), 256, 0, stream>>>(yn, wgb, wgb, wgb, gb, gb, gb,
                                                     nullptr, nullptr, nullptr, 8192, 2048);
  // 8. up GEMM, epilogue silu(gate)*up in-place into gb
  gemm_nt<2, 4><<<dim3(64, 16, 1), 256, 0, stream>>>(yn, wub, wub, wub, gb, gb, gb,
                                                     gb, nullptr, nullptr, 8192, 2048);
  // 9. down GEMM + h residual -> out (f32)
  gemm_nt<1, 2><<<dim3(16, 32, 1), 256, 0, stream>>>(gb, wdb, wdb, wdb,
                                                     nullptr, nullptr, nullptr,
                                                     nullptr, hf, outp, 2048, 8192);
}

// Round 3
// 844.460 us; speedup vs baseline: 1.0497x; 1.0497x over previous
//
#include <hip/hip_runtime.h>
#include <cstdint>
#include <cstddef>

typedef __bf16 bf16x8 __attribute__((ext_vector_type(8)));
typedef float f32x4 __attribute__((ext_vector_type(4)));

union V16 { uint4 u; bf16x8 b; unsigned short s[8]; };

__device__ __forceinline__ float b2f(unsigned short u) {
  unsigned int x = ((unsigned int)u) << 16;
  float f;
  __builtin_memcpy(&f, &x, 4);
  return f;
}
__device__ __forceinline__ unsigned short f2b(float f) {
  unsigned int u;
  __builtin_memcpy(&u, &f, 4);
  u = u + 0x7FFFu + ((u >> 16) & 1u);
  return (unsigned short)(u >> 16);
}

__device__ __forceinline__ f32x4 mfma16(bf16x8 a, bf16x8 b, f32x4 c) {
  return __builtin_amdgcn_mfma_f32_16x16x32_bf16(a, b, c, 0, 0, 0);
}

// async global->LDS, 16B per lane; LDS dest is wave-uniform base (+lane*16 implicit)
__device__ __forceinline__ void gld_lds16(const unsigned short* g, unsigned short* l) {
  __builtin_amdgcn_global_load_lds((__attribute__((address_space(1))) void*)g,
                                   (__attribute__((address_space(3))) void*)l,
                                   16, 0, 0);
}

// ---------------- f32 -> bf16 convert ----------------
__global__ __launch_bounds__(256) void cvt_k(const float* __restrict__ in,
                                             unsigned short* __restrict__ out, int n) {
  const int i = (blockIdx.x * 256 + threadIdx.x) * 4;
  if (i + 3 < n) {
    const float4 v = *(const float4*)(in + i);
    ushort4 o;
    o.x = f2b(v.x); o.y = f2b(v.y); o.z = f2b(v.z); o.w = f2b(v.w);
    *(ushort4*)(out + i) = o;
  }
}

// ---------------- RMSNorm (f32 in -> bf16 out) ----------------
__global__ __launch_bounds__(256) void rms_k(const float* __restrict__ xin,
                                             const float* __restrict__ wgt,
                                             unsigned short* __restrict__ out) {
  const int s = blockIdx.x;
  const int t = threadIdx.x;
  float vals[8];
  float ss = 0.f;
#pragma unroll
  for (int i = 0; i < 8; ++i) {
    const int c = t + i * 256;
    const float f = xin[(size_t)s * 2048 + c];
    vals[i] = f;
    ss += f * f;
  }
#pragma unroll
  for (int off = 32; off > 0; off >>= 1) ss += __shfl_xor(ss, off);
  __shared__ float red[4];
  if ((t & 63) == 0) red[t >> 6] = ss;
  __syncthreads();
  ss = red[0] + red[1] + red[2] + red[3];
  const float sc = rsqrtf(ss * (1.f / 2048.f) + 1e-6f);
#pragma unroll
  for (int i = 0; i < 8; ++i) {
    const int c = t + i * 256;
    out[(size_t)s * 2048 + c] = f2b(vals[i] * sc * wgt[c]);
  }
}

// ---------------- RoPE (in-place bf16 q,k) + k^2*c precompute ----------------
__global__ __launch_bounds__(256) void rope_qk(unsigned short* qb, unsigned short* kb,
                                               const float* __restrict__ cosb,
                                               const float* __restrict__ sinb,
                                               float* __restrict__ k2c) {
  const int idx = blockIdx.x * 256 + threadIdx.x;  // 0 .. S*H*64
  const int d = idx & 63;
  const int h = (idx >> 6) & 15;
  const int s = idx >> 10;
  const size_t base = (size_t)s * 2048 + h * 128;
  const int cb = s * 128;
  const float c1 = cosb[cb + d],      s1 = sinb[cb + d];
  const float c2 = cosb[cb + d + 64], s2 = sinb[cb + d + 64];
  {
    const float x1 = b2f(qb[base + d]), x2 = b2f(qb[base + d + 64]);
    qb[base + d]      = f2b(x1 * c1 - x2 * s1);
    qb[base + d + 64] = f2b(x2 * c2 + x1 * s2);
  }
  {
    const float x1 = b2f(kb[base + d]), x2 = b2f(kb[base + d + 64]);
    const float k1 = x1 * c1 - x2 * s1;
    const float k2 = x2 * c2 + x1 * s2;
    kb[base + d]      = f2b(k1);
    kb[base + d + 64] = f2b(k2);
    // ||k||^2 * (1/(2*sqrt(D))) for this (s,h); 64 lanes = one (s,h) group
    float ss = k1 * k1 + k2 * k2;
#pragma unroll
    for (int off = 32; off > 0; off >>= 1) ss += __shfl_xor(ss, off);
    if (d == 0) k2c[h * 2048 + s] = ss * 0.04419417382415922f;
  }
}

// ---------------- NT GEMM: C[M,N] = A[M,K] @ B[N,K]^T (bf16 in, f32 acc) ----------------
// EPI 0: C=bf16(acc)   1: Cf=auxf+acc (f32 store)   2: C=bf16(silu(auxb)*acc)
template <int EPI, int RT>
__global__ __launch_bounds__(256, 2) void gemm_nt(
    const unsigned short* __restrict__ A,
    const unsigned short* __restrict__ B0,
    const unsigned short* __restrict__ B1,
    const unsigned short* __restrict__ B2,
    unsigned short* C0, unsigned short* C1, unsigned short* C2,
    const unsigned short* auxb, const float* auxf, float* Cf,
    int N, int K) {
  constexpr int TM = RT * 32;
  constexpr int APASS = TM / 64;
  const unsigned short* B = (blockIdx.z == 0) ? B0 : (blockIdx.z == 1 ? B1 : B2);
  unsigned short* C = (blockIdx.z == 0) ? C0 : (blockIdx.z == 1 ? C1 : C2);

  const int m0 = blockIdx.y * TM;
  const int n0 = blockIdx.x * 128;
  const int t = threadIdx.x;
  const int lane = t & 63;
  const int w = t >> 6;
  const int quad = lane >> 4;
  const int l15 = lane & 15;
  const int wr = w >> 1;
  const int wc = w & 1;

  __shared__ __align__(16) unsigned short As[TM * 32];
  __shared__ __align__(16) unsigned short Bs[128 * 32];

  const f32x4 vzero = {0.f, 0.f, 0.f, 0.f};
  f32x4 acc[RT][4];
#pragma unroll
  for (int i = 0; i < RT; ++i)
#pragma unroll
    for (int j = 0; j < 4; ++j) acc[i][j] = vzero;

  const int srow = w * 16 + (lane >> 2);
  const int scol = (lane & 3) * 8;
  const unsigned short* Ag = A + (size_t)(m0 + srow) * K + scol;
  const unsigned short* Bg = B + (size_t)(n0 + srow) * K + scol;

  for (int k0 = 0; k0 < K; k0 += 32) {
#pragma unroll
    for (int p = 0; p < APASS; ++p)
      gld_lds16(Ag + (size_t)p * 64 * K + k0, As + p * 2048 + w * 512);
#pragma unroll
    for (int p = 0; p < 2; ++p)
      gld_lds16(Bg + (size_t)p * 64 * K + k0, Bs + p * 2048 + w * 512);
    __syncthreads();

    bf16x8 af[RT], bfr[4];
#pragma unroll
    for (int rt = 0; rt < RT; ++rt)
      af[rt] = *(const bf16x8*)&As[(wr * (RT * 16) + rt * 16 + l15) * 32 + quad * 8];
#pragma unroll
    for (int ct = 0; ct < 4; ++ct)
      bfr[ct] = *(const bf16x8*)&Bs[(wc * 64 + ct * 16 + l15) * 32 + quad * 8];
#pragma unroll
    for (int rt = 0; rt < RT; ++rt)
#pragma unroll
      for (int ct = 0; ct < 4; ++ct)
        acc[rt][ct] = mfma16(af[rt], bfr[ct], acc[rt][ct]);
    __syncthreads();
  }

#pragma unroll
  for (int rt = 0; rt < RT; ++rt) {
#pragma unroll
    for (int ct = 0; ct < 4; ++ct) {
#pragma unroll
      for (int r = 0; r < 4; ++r) {
        const int m = m0 + wr * (RT * 16) + rt * 16 + quad * 4 + r;
        const int n = n0 + wc * 64 + ct * 16 + l15;
        const size_t idx = (size_t)m * N + n;
        const float a = acc[rt][ct][r];
        if constexpr (EPI == 0) {
          C[idx] = f2b(a);
        } else if constexpr (EPI == 1) {
          Cf[idx] = auxf[idx] + a;
        } else {
          const float g = b2f(auxb[idx]);
          const float sg = g / (1.f + __expf(-g));
          C[idx] = f2b(sg * a);
        }
      }
    }
  }
}

// ---------------- Flash W2 (Gaussian-kernel) attention ----------------
// grid (32, 16). Work-balanced: logical q-tile i = (h>=8) ? 31-bx : bx, so each
// CU's two blocks total 33 j-tiles. Wave w handles q rows [i0+16w, i0+16w+16).
// scores = 2c*qk - c*k^2 (q^2 dropped: per-row constant cancels in softmax).
__global__ __launch_bounds__(256, 3) void flash_w2(
    const unsigned short* __restrict__ q,
    const unsigned short* __restrict__ kk,
    const unsigned short* __restrict__ v,
    const float* __restrict__ k2c,
    unsigned short* __restrict__ ctx) {
  constexpr int Cw = 2048;
  constexpr float TWOC = 0.08838834764831843f;  // 1/sqrt(128)
  const int h = blockIdx.y;
  const int i = (h >= 8) ? (31 - blockIdx.x) : blockIdx.x;
  const int i0 = i * 64;
  const int t = threadIdx.x;
  const int lane = t & 63;
  const int w = t >> 6;
  const int quad = lane >> 4;
  const int l15 = lane & 15;

  __shared__ __align__(16) unsigned short Ks[64 * 136];   // [j][d], pitch 136
  __shared__ __align__(16) unsigned short VTs[128 * 72];  // [d][j^], pitch 72, j-group XOR-swizzled by d>>4
  __shared__ __align__(16) unsigned short Ps[4][16 * 72]; // per-wave P, pitch 72

  // Q fragments (A-layout: row=l15, k=quad*8+j)
  bf16x8 aq[4];
  {
    const unsigned short* qp = q + (size_t)(i0 + w * 16 + l15) * Cw + h * 128;
#pragma unroll
    for (int kt = 0; kt < 4; ++kt) {
      V16 u;
      u.u = *(const uint4*)(qp + kt * 32 + quad * 8);
      aq[kt] = u.b;
    }
  }

  const f32x4 vzero = {0.f, 0.f, 0.f, 0.f};
  f32x4 o[8];
#pragma unroll
  for (int nt = 0; nt < 8; ++nt) o[nt] = vzero;
  float mrow[4] = {-1e30f, -1e30f, -1e30f, -1e30f};
  float lrow[4] = {0.f, 0.f, 0.f, 0.f};

  const int njt = i + 1;
  const int jr = t >> 2;          // staging row 0..63
  const int c0 = (t & 3) * 32;    // staging col group
  const int jlo = jr & 7;
  const int jhi = jr >> 3;
  for (int jt = 0; jt < njt; ++jt) {
    const int j0 = jt * 64;
    __syncthreads();
    {  // stage K tile and swizzled V^T tile
      const unsigned short* kp = kk + (size_t)(j0 + jr) * Cw + h * 128 + c0;
      const unsigned short* vp = v + (size_t)(j0 + jr) * Cw + h * 128 + c0;
#pragma unroll
      for (int ii = 0; ii < 4; ++ii) {
        *(uint4*)&Ks[jr * 136 + c0 + ii * 8] = *(const uint4*)(kp + ii * 8);
        V16 vu;
        vu.u = *(const uint4*)(vp + ii * 8);
#pragma unroll
        for (int e = 0; e < 8; ++e) {
          const int dd = c0 + ii * 8 + e;
          const int gs = (jhi ^ (dd >> 4)) & 7;
          VTs[dd * 72 + (jlo | (gs << 3))] = vu.s[e];
        }
      }
    }
    __syncthreads();

    // k2 column values
    float k2v[4];
#pragma unroll
    for (int ct = 0; ct < 4; ++ct) k2v[ct] = k2c[h * 2048 + j0 + ct * 16 + l15];

    // S = Q K^T (16x64 per wave)
    f32x4 sc[4];
#pragma unroll
    for (int ct = 0; ct < 4; ++ct) {
      f32x4 a = vzero;
#pragma unroll
      for (int kt = 0; kt < 4; ++kt) {
        V16 u;
        u.u = *(const uint4*)&Ks[(ct * 16 + l15) * 136 + kt * 32 + quad * 8];
        a = mfma16(aq[kt], u.b, a);
      }
      sc[ct] = a;
    }

    // scores; causal mask only needed on the diagonal tile
    const bool diag = (jt == njt - 1);
#pragma unroll
    for (int ct = 0; ct < 4; ++ct) {
#pragma unroll
      for (int r = 0; r < 4; ++r) {
        float s = fmaf(TWOC, sc[ct][r], -k2v[ct]);
        if (diag) {
          const int gi = w * 16 + quad * 4 + r;
          const int gj = ct * 16 + l15;
          s = (gj <= gi) ? s : -1e30f;
        }
        sc[ct][r] = s;
      }
    }

    // online softmax (rows live in 16-lane quad groups x 4 regs)
    float al[4];
#pragma unroll
    for (int r = 0; r < 4; ++r) {
      float rm = fmaxf(fmaxf(sc[0][r], sc[1][r]), fmaxf(sc[2][r], sc[3][r]));
      rm = fmaxf(rm, __shfl_xor(rm, 1));
      rm = fmaxf(rm, __shfl_xor(rm, 2));
      rm = fmaxf(rm, __shfl_xor(rm, 4));
      rm = fmaxf(rm, __shfl_xor(rm, 8));
      const float mn = fmaxf(mrow[r], rm);
      al[r] = __expf(mrow[r] - mn);
      mrow[r] = mn;
      float ps = 0.f;
#pragma unroll
      for (int ct = 0; ct < 4; ++ct) {
        const float p = __expf(sc[ct][r] - mn);
        sc[ct][r] = p;
        ps += p;
      }
      ps += __shfl_xor(ps, 1);
      ps += __shfl_xor(ps, 2);
      ps += __shfl_xor(ps, 4);
      ps += __shfl_xor(ps, 8);
      lrow[r] = lrow[r] * al[r] + ps;
    }
#pragma unroll
    for (int nt = 0; nt < 8; ++nt)
#pragma unroll
      for (int r = 0; r < 4; ++r) o[nt][r] *= al[r];

    // P -> per-wave LDS (C-layout write, A-layout read; no barrier needed)
#pragma unroll
    for (int ct = 0; ct < 4; ++ct)
#pragma unroll
      for (int r = 0; r < 4; ++r)
        Ps[w][(quad * 4 + r) * 72 + ct * 16 + l15] = f2b(sc[ct][r]);

    // O += P V  (V^T frags read through the XOR swizzle: group g -> g ^ nt)
#pragma unroll
    for (int kt2 = 0; kt2 < 2; ++kt2) {
      V16 pa;
      pa.u = *(const uint4*)&Ps[w][l15 * 72 + kt2 * 32 + quad * 8];
#pragma unroll
      for (int nt = 0; nt < 8; ++nt) {
        V16 vb;
        const int dd = nt * 16 + l15;
        const int gs = (kt2 * 4 + quad) ^ nt;
        vb.u = *(const uint4*)&VTs[dd * 72 + gs * 8];
        o[nt] = mfma16(pa.b, vb.b, o[nt]);
      }
    }
  }

  float invl[4];
#pragma unroll
  for (int r = 0; r < 4; ++r) invl[r] = 1.f / lrow[r];
#pragma unroll
  for (int nt = 0; nt < 8; ++nt) {
#pragma unroll
    for (int r = 0; r < 4; ++r) {
      const int gi = i0 + w * 16 + quad * 4 + r;
      ctx[(size_t)gi * Cw + h * 128 + nt * 16 + l15] = f2b(o[nt][r] * invl[r]);
    }
  }
}

// ---------------- driver ----------------
extern "C" void kernel_launch(void* const* d_in, const int* in_sizes, int n_in,
                              void* d_out, int out_size, void* d_ws, size_t ws_size,
                              hipStream_t stream) {
  (void)in_sizes; (void)n_in; (void)out_size; (void)ws_size;
  const float* hid  = (const float*)d_in[0];
  const float* cosb = (const float*)d_in[1];
  const float* sinb = (const float*)d_in[2];
  // d_in[3] attention_mask: exactly causal -> applied analytically
  const float* ln1w = (const float*)d_in[4];
  const float* wq   = (const float*)d_in[5];
  const float* wk   = (const float*)d_in[6];
  const float* wv   = (const float*)d_in[7];
  const float* wo   = (const float*)d_in[8];
  const float* ln2w = (const float*)d_in[9];
  const float* wg   = (const float*)d_in[10];
  const float* wu   = (const float*)d_in[11];
  const float* wd   = (const float*)d_in[12];
  float* outp = (float*)d_out;

  const size_t SC = (size_t)2048 * 2048;       // 4.19M
  const size_t FC = (size_t)8192 * 2048;       // 16.78M
  unsigned short* p = (unsigned short*)d_ws;
  unsigned short* wqb = p;  p += SC;
  unsigned short* wkb = p;  p += SC;
  unsigned short* wvb = p;  p += SC;
  unsigned short* wob = p;  p += SC;
  unsigned short* wgb = p;  p += FC;
  unsigned short* wub = p;  p += FC;
  unsigned short* wdb = p;  p += FC;
  unsigned short* xn  = p;  p += SC;           // also reused as yn
  unsigned short* qb  = p;  p += SC;
  unsigned short* kb  = p;  p += SC;
  unsigned short* vb  = p;  p += SC;
  unsigned short* ctxb = p; p += SC;
  float* hf = (float*)p;   p += 2 * SC;         // f32 h = hidden + attn_out
  float* k2cb = (float*)p;                      // [H][S] = k^2 * c
  unsigned short* yn = xn;                      // xn dead after QKV
  unsigned short* gb = qb;                      // qb..ctxb (4*SC == FC) dead after wo-proj

  // 0. weights f32 -> bf16
  cvt_k<<<(int)(SC / 1024), 256, 0, stream>>>(wq, wqb, (int)SC);
  cvt_k<<<(int)(SC / 1024), 256, 0, stream>>>(wk, wkb, (int)SC);
  cvt_k<<<(int)(SC / 1024), 256, 0, stream>>>(wv, wvb, (int)SC);
  cvt_k<<<(int)(SC / 1024), 256, 0, stream>>>(wo, wob, (int)SC);
  cvt_k<<<(int)(FC / 1024), 256, 0, stream>>>(wg, wgb, (int)FC);
  cvt_k<<<(int)(FC / 1024), 256, 0, stream>>>(wu, wub, (int)FC);
  cvt_k<<<(int)(FC / 1024), 256, 0, stream>>>(wd, wdb, (int)FC);

  // 1. input RMSNorm
  rms_k<<<2048, 256, 0, stream>>>(hid, ln1w, xn);
  // 2. fused QKV projection (gridDim.z selects weight/output)
  gemm_nt<0, 4><<<dim3(16, 16, 3), 256, 0, stream>>>(xn, wqb, wkb, wvb, qb, kb, vb,
                                                     nullptr, nullptr, nullptr, 2048, 2048);
  // 3. RoPE in-place on q,k + k^2*c precompute
  rope_qk<<<8192, 256, 0, stream>>>(qb, kb, cosb, sinb, k2cb);
  // 4. W2 attention -> ctx
  flash_w2<<<dim3(32, 16), 256, 0, stream>>>(qb, kb, vb, k2cb, ctxb);
  // 5. output projection + residual -> h (f32)
  gemm_nt<1, 2><<<dim3(16, 32, 1), 256, 0, stream>>>(ctxb, wob, wob, wob,
                                                     nullptr, nullptr, nullptr,
                                                     nullptr, hid, hf, 2048, 2048);
  // 6. post-attn RMSNorm
  rms_k<<<2048, 256, 0, stream>>>(hf, ln2w, yn);
  // 7. gate GEMM
  gemm_nt<0, 4><<<dim3(64, 16, 1), 256, 0, stream>>>(yn, wgb, wgb, wgb, gb, gb, gb,
                                                     nullptr, nullptr, nullptr, 8192, 2048);
  // 8. up GEMM, epilogue silu(gate)*up in-place into gb
  gemm_nt<2, 4><<<dim3(64, 16, 1), 256, 0, stream>>>(yn, wub, wub, wub, gb, gb, gb,
                                                     gb, nullptr, nullptr, 8192, 2048);
  // 9. down GEMM + h residual -> out (f32)
  gemm_nt<1, 2><<<dim3(16, 32, 1), 256, 0, stream>>>(gb, wdb, wdb, wdb,
                                                     nullptr, nullptr, nullptr,
                                                     nullptr, hf, outp, 2048, 8192);
}

// Round 4
// 809.515 us; speedup vs baseline: 1.0950x; 1.0432x over previous
//
#include <hip/hip_runtime.h>
#include <cstdint>
#include <cstddef>

typedef __bf16 bf16x8 __attribute__((ext_vector_type(8)));
typedef float f32x4 __attribute__((ext_vector_type(4)));

union V16 { uint4 u; bf16x8 b; unsigned short s[8]; };

__device__ __forceinline__ float b2f(unsigned short u) {
  unsigned int x = ((unsigned int)u) << 16;
  float f;
  __builtin_memcpy(&f, &x, 4);
  return f;
}
__device__ __forceinline__ unsigned short f2b(float f) {
  unsigned int u;
  __builtin_memcpy(&u, &f, 4);
  u = u + 0x7FFFu + ((u >> 16) & 1u);
  return (unsigned short)(u >> 16);
}

__device__ __forceinline__ f32x4 mfma16(bf16x8 a, bf16x8 b, f32x4 c) {
  return __builtin_amdgcn_mfma_f32_16x16x32_bf16(a, b, c, 0, 0, 0);
}

// async global->LDS, 16B per lane; LDS dest is wave-uniform base (+lane*16 implicit)
__device__ __forceinline__ void gld_lds16(const unsigned short* g, unsigned short* l) {
  __builtin_amdgcn_global_load_lds((__attribute__((address_space(1))) void*)g,
                                   (__attribute__((address_space(3))) void*)l,
                                   16, 0, 0);
}

// ---------------- merged f32 -> bf16 convert (all 7 weights, contiguous dst) ----------------
// block = 1024 elems. Ranges: wq/wk/wv/wo 4096 blocks each, wg/wu/wd 16384 each.
__global__ __launch_bounds__(256) void cvt_all(const float* __restrict__ wq,
                                               const float* __restrict__ wk,
                                               const float* __restrict__ wv,
                                               const float* __restrict__ wo,
                                               const float* __restrict__ wg,
                                               const float* __restrict__ wu,
                                               const float* __restrict__ wd,
                                               unsigned short* __restrict__ dst) {
  const int b = blockIdx.x;
  const float* src;
  if (b < 16384) {
    const int w = b >> 12;
    src = (w == 0 ? wq : w == 1 ? wk : w == 2 ? wv : wo) + (size_t)(b & 4095) * 1024;
  } else if (b < 32768) {
    src = wg + (size_t)(b - 16384) * 1024;
  } else if (b < 49152) {
    src = wu + (size_t)(b - 32768) * 1024;
  } else {
    src = wd + (size_t)(b - 49152) * 1024;
  }
  const int o = threadIdx.x * 4;
  const float4 v = *(const float4*)(src + o);
  ushort4 r;
  r.x = f2b(v.x); r.y = f2b(v.y); r.z = f2b(v.z); r.w = f2b(v.w);
  *(ushort4*)(dst + (size_t)b * 1024 + o) = r;
}

// ---------------- RMSNorm (f32 in -> bf16 out) ----------------
__global__ __launch_bounds__(256) void rms_k(const float* __restrict__ xin,
                                             const float* __restrict__ wgt,
                                             unsigned short* __restrict__ out) {
  const int s = blockIdx.x;
  const int t = threadIdx.x;
  float vals[8];
  float ss = 0.f;
#pragma unroll
  for (int i = 0; i < 8; ++i) {
    const int c = t + i * 256;
    const float f = xin[(size_t)s * 2048 + c];
    vals[i] = f;
    ss += f * f;
  }
#pragma unroll
  for (int off = 32; off > 0; off >>= 1) ss += __shfl_xor(ss, off);
  __shared__ float red[4];
  if ((t & 63) == 0) red[t >> 6] = ss;
  __syncthreads();
  ss = red[0] + red[1] + red[2] + red[3];
  const float sc = rsqrtf(ss * (1.f / 2048.f) + 1e-6f);
#pragma unroll
  for (int i = 0; i < 8; ++i) {
    const int c = t + i * 256;
    out[(size_t)s * 2048 + c] = f2b(vals[i] * sc * wgt[c]);
  }
}

// ---------------- RoPE (in-place bf16 q,k) + k^2*c precompute ----------------
__global__ __launch_bounds__(256) void rope_qk(unsigned short* qb, unsigned short* kb,
                                               const float* __restrict__ cosb,
                                               const float* __restrict__ sinb,
                                               float* __restrict__ k2c) {
  const int idx = blockIdx.x * 256 + threadIdx.x;  // 0 .. S*H*64
  const int d = idx & 63;
  const int h = (idx >> 6) & 15;
  const int s = idx >> 10;
  const size_t base = (size_t)s * 2048 + h * 128;
  const int cb = s * 128;
  const float c1 = cosb[cb + d],      s1 = sinb[cb + d];
  const float c2 = cosb[cb + d + 64], s2 = sinb[cb + d + 64];
  {
    const float x1 = b2f(qb[base + d]), x2 = b2f(qb[base + d + 64]);
    qb[base + d]      = f2b(x1 * c1 - x2 * s1);
    qb[base + d + 64] = f2b(x2 * c2 + x1 * s2);
  }
  {
    const float x1 = b2f(kb[base + d]), x2 = b2f(kb[base + d + 64]);
    const float k1 = x1 * c1 - x2 * s1;
    const float k2 = x2 * c2 + x1 * s2;
    kb[base + d]      = f2b(k1);
    kb[base + d + 64] = f2b(k2);
    float ss = k1 * k1 + k2 * k2;
#pragma unroll
    for (int off = 32; off > 0; off >>= 1) ss += __shfl_xor(ss, off);
    if (d == 0) k2c[h * 2048 + s] = ss * 0.04419417382415922f;
  }
}

// ---------------- NT GEMM: C[M,N] = A[M,K] @ B[N,K]^T (bf16 in, f32 acc) ----------------
// EPI 0: C=bf16(acc), blockIdx.z selects B/C (QKV fusion)
// EPI 1: Cf[idx] = auxf[idx] + acc (f32 store)
// EPI 3: split-K partial: Cf + z*M*N, A/B offset by z*K (kstride = full K)
template <int EPI, int RT>
__global__ __launch_bounds__(256, 2) void gemm_nt(
    const unsigned short* __restrict__ A,
    const unsigned short* __restrict__ B0,
    const unsigned short* __restrict__ B1,
    const unsigned short* __restrict__ B2,
    unsigned short* C0, unsigned short* C1, unsigned short* C2,
    const float* auxf, float* Cf,
    int N, int K, int kstride) {
  constexpr int TM = RT * 32;
  constexpr int APASS = TM / 64;
  const unsigned short* B;
  unsigned short* C;
  size_t koff = 0;
  if constexpr (EPI == 0) {
    B = (blockIdx.z == 0) ? B0 : (blockIdx.z == 1 ? B1 : B2);
    C = (blockIdx.z == 0) ? C0 : (blockIdx.z == 1 ? C1 : C2);
  } else {
    B = B0;
    C = C0;
    if constexpr (EPI == 3) koff = (size_t)blockIdx.z * K;
  }

  const int m0 = blockIdx.y * TM;
  const int n0 = blockIdx.x * 128;
  const int t = threadIdx.x;
  const int lane = t & 63;
  const int w = t >> 6;
  const int quad = lane >> 4;
  const int l15 = lane & 15;
  const int wr = w >> 1;
  const int wc = w & 1;

  __shared__ __align__(16) unsigned short As[TM * 32];
  __shared__ __align__(16) unsigned short Bs[128 * 32];

  const f32x4 vzero = {0.f, 0.f, 0.f, 0.f};
  f32x4 acc[RT][4];
#pragma unroll
  for (int i = 0; i < RT; ++i)
#pragma unroll
    for (int j = 0; j < 4; ++j) acc[i][j] = vzero;

  const int srow = w * 16 + (lane >> 2);
  const int scol = (lane & 3) * 8;
  const unsigned short* Ag = A + (size_t)(m0 + srow) * kstride + scol + koff;
  const unsigned short* Bg = B + (size_t)(n0 + srow) * kstride + scol + koff;

  for (int k0 = 0; k0 < K; k0 += 32) {
#pragma unroll
    for (int p = 0; p < APASS; ++p)
      gld_lds16(Ag + (size_t)p * 64 * kstride + k0, As + p * 2048 + w * 512);
#pragma unroll
    for (int p = 0; p < 2; ++p)
      gld_lds16(Bg + (size_t)p * 64 * kstride + k0, Bs + p * 2048 + w * 512);
    __syncthreads();

    bf16x8 af[RT], bfr[4];
#pragma unroll
    for (int rt = 0; rt < RT; ++rt)
      af[rt] = *(const bf16x8*)&As[(wr * (RT * 16) + rt * 16 + l15) * 32 + quad * 8];
#pragma unroll
    for (int ct = 0; ct < 4; ++ct)
      bfr[ct] = *(const bf16x8*)&Bs[(wc * 64 + ct * 16 + l15) * 32 + quad * 8];
#pragma unroll
    for (int rt = 0; rt < RT; ++rt)
#pragma unroll
      for (int ct = 0; ct < 4; ++ct)
        acc[rt][ct] = mfma16(af[rt], bfr[ct], acc[rt][ct]);
    __syncthreads();
  }

  float* Cfz = Cf;
  if constexpr (EPI == 3)
    Cfz = Cf + (size_t)blockIdx.z * (size_t)gridDim.y * TM * N;

#pragma unroll
  for (int rt = 0; rt < RT; ++rt) {
#pragma unroll
    for (int ct = 0; ct < 4; ++ct) {
#pragma unroll
      for (int r = 0; r < 4; ++r) {
        const int m = m0 + wr * (RT * 16) + rt * 16 + quad * 4 + r;
        const int n = n0 + wc * 64 + ct * 16 + l15;
        const size_t idx = (size_t)m * N + n;
        const float a = acc[rt][ct][r];
        if constexpr (EPI == 0) {
          C[idx] = f2b(a);
        } else if constexpr (EPI == 1) {
          Cf[idx] = auxf[idx] + a;
        } else {
          Cfz[idx] = a;
        }
      }
    }
  }
}

// ---------------- dual-B NT GEMM: gate+up fused, epilogue silu(g)*u ----------------
// C[M,N] = silu(A@B0^T) * (A@B1^T), 128x128 tile, 32 MFMA per barrier pair.
__global__ __launch_bounds__(256, 2) void gemm_nt2(
    const unsigned short* __restrict__ A,
    const unsigned short* __restrict__ B0,
    const unsigned short* __restrict__ B1,
    unsigned short* __restrict__ C,
    int N, int K) {
  const int m0 = blockIdx.y * 128;
  const int n0 = blockIdx.x * 128;
  const int t = threadIdx.x;
  const int lane = t & 63;
  const int w = t >> 6;
  const int quad = lane >> 4;
  const int l15 = lane & 15;
  const int wr = w >> 1;
  const int wc = w & 1;

  __shared__ __align__(16) unsigned short As[128 * 32];
  __shared__ __align__(16) unsigned short B0s[128 * 32];
  __shared__ __align__(16) unsigned short B1s[128 * 32];

  const f32x4 vzero = {0.f, 0.f, 0.f, 0.f};
  f32x4 acc0[4][4], acc1[4][4];
#pragma unroll
  for (int i = 0; i < 4; ++i)
#pragma unroll
    for (int j = 0; j < 4; ++j) { acc0[i][j] = vzero; acc1[i][j] = vzero; }

  const int srow = w * 16 + (lane >> 2);
  const int scol = (lane & 3) * 8;
  const unsigned short* Ag  = A  + (size_t)(m0 + srow) * K + scol;
  const unsigned short* B0g = B0 + (size_t)(n0 + srow) * K + scol;
  const unsigned short* B1g = B1 + (size_t)(n0 + srow) * K + scol;

  for (int k0 = 0; k0 < K; k0 += 32) {
#pragma unroll
    for (int p = 0; p < 2; ++p) {
      gld_lds16(Ag  + (size_t)p * 64 * K + k0, As  + p * 2048 + w * 512);
      gld_lds16(B0g + (size_t)p * 64 * K + k0, B0s + p * 2048 + w * 512);
      gld_lds16(B1g + (size_t)p * 64 * K + k0, B1s + p * 2048 + w * 512);
    }
    __syncthreads();

    bf16x8 af[4], b0f[4], b1f[4];
#pragma unroll
    for (int rt = 0; rt < 4; ++rt)
      af[rt] = *(const bf16x8*)&As[(wr * 64 + rt * 16 + l15) * 32 + quad * 8];
#pragma unroll
    for (int ct = 0; ct < 4; ++ct) {
      b0f[ct] = *(const bf16x8*)&B0s[(wc * 64 + ct * 16 + l15) * 32 + quad * 8];
      b1f[ct] = *(const bf16x8*)&B1s[(wc * 64 + ct * 16 + l15) * 32 + quad * 8];
    }
#pragma unroll
    for (int rt = 0; rt < 4; ++rt)
#pragma unroll
      for (int ct = 0; ct < 4; ++ct) {
        acc0[rt][ct] = mfma16(af[rt], b0f[ct], acc0[rt][ct]);
        acc1[rt][ct] = mfma16(af[rt], b1f[ct], acc1[rt][ct]);
      }
    __syncthreads();
  }

#pragma unroll
  for (int rt = 0; rt < 4; ++rt) {
#pragma unroll
    for (int ct = 0; ct < 4; ++ct) {
#pragma unroll
      for (int r = 0; r < 4; ++r) {
        const int m = m0 + wr * 64 + rt * 16 + quad * 4 + r;
        const int n = n0 + wc * 64 + ct * 16 + l15;
        const float g = acc0[rt][ct][r];
        const float u = acc1[rt][ct][r];
        const float sg = g / (1.f + __expf(-g));
        C[(size_t)m * N + n] = f2b(sg * u);
      }
    }
  }
}

// ---------------- split-K combine: out = hf + q0 + q1 ----------------
__global__ __launch_bounds__(256) void comb_k(const float* __restrict__ q0,
                                              const float* __restrict__ q1,
                                              const float* __restrict__ hf,
                                              float* __restrict__ out) {
  const int i = (blockIdx.x * 256 + threadIdx.x) * 4;
  const float4 a = *(const float4*)(q0 + i);
  const float4 b = *(const float4*)(q1 + i);
  const float4 c = *(const float4*)(hf + i);
  float4 r;
  r.x = a.x + b.x + c.x; r.y = a.y + b.y + c.y;
  r.z = a.z + b.z + c.z; r.w = a.w + b.w + c.w;
  *(float4*)(out + i) = r;
}

// ---------------- Flash W2 (Gaussian-kernel) attention ----------------
__global__ __launch_bounds__(256, 3) void flash_w2(
    const unsigned short* __restrict__ q,
    const unsigned short* __restrict__ kk,
    const unsigned short* __restrict__ v,
    const float* __restrict__ k2c,
    unsigned short* __restrict__ ctx) {
  constexpr int Cw = 2048;
  constexpr float TWOC = 0.08838834764831843f;  // 1/sqrt(128)
  const int h = blockIdx.y;
  const int i = (h >= 8) ? (31 - blockIdx.x) : blockIdx.x;
  const int i0 = i * 64;
  const int t = threadIdx.x;
  const int lane = t & 63;
  const int w = t >> 6;
  const int quad = lane >> 4;
  const int l15 = lane & 15;

  __shared__ __align__(16) unsigned short Ks[64 * 136];   // [j][d], pitch 136
  __shared__ __align__(16) unsigned short VTs[128 * 72];  // [d][j^], XOR-swizzled
  __shared__ __align__(16) unsigned short Ps[4][16 * 72]; // per-wave P

  bf16x8 aq[4];
  {
    const unsigned short* qp = q + (size_t)(i0 + w * 16 + l15) * Cw + h * 128;
#pragma unroll
    for (int kt = 0; kt < 4; ++kt) {
      V16 u;
      u.u = *(const uint4*)(qp + kt * 32 + quad * 8);
      aq[kt] = u.b;
    }
  }

  const f32x4 vzero = {0.f, 0.f, 0.f, 0.f};
  f32x4 o[8];
#pragma unroll
  for (int nt = 0; nt < 8; ++nt) o[nt] = vzero;
  float mrow[4] = {-1e30f, -1e30f, -1e30f, -1e30f};
  float lrow[4] = {0.f, 0.f, 0.f, 0.f};

  const int njt = i + 1;
  const int jr = t >> 2;
  const int c0 = (t & 3) * 32;
  const int jlo = jr & 7;
  const int jhi = jr >> 3;
  for (int jt = 0; jt < njt; ++jt) {
    const int j0 = jt * 64;
    __syncthreads();
    {
      const unsigned short* kp = kk + (size_t)(j0 + jr) * Cw + h * 128 + c0;
      const unsigned short* vp = v + (size_t)(j0 + jr) * Cw + h * 128 + c0;
#pragma unroll
      for (int ii = 0; ii < 4; ++ii) {
        *(uint4*)&Ks[jr * 136 + c0 + ii * 8] = *(const uint4*)(kp + ii * 8);
        V16 vu;
        vu.u = *(const uint4*)(vp + ii * 8);
#pragma unroll
        for (int e = 0; e < 8; ++e) {
          const int dd = c0 + ii * 8 + e;
          const int gs = (jhi ^ (dd >> 4)) & 7;
          VTs[dd * 72 + (jlo | (gs << 3))] = vu.s[e];
        }
      }
    }
    __syncthreads();

    float k2v[4];
#pragma unroll
    for (int ct = 0; ct < 4; ++ct) k2v[ct] = k2c[h * 2048 + j0 + ct * 16 + l15];

    f32x4 sc[4];
#pragma unroll
    for (int ct = 0; ct < 4; ++ct) {
      f32x4 a = vzero;
#pragma unroll
      for (int kt = 0; kt < 4; ++kt) {
        V16 u;
        u.u = *(const uint4*)&Ks[(ct * 16 + l15) * 136 + kt * 32 + quad * 8];
        a = mfma16(aq[kt], u.b, a);
      }
      sc[ct] = a;
    }

    const bool diag = (jt == njt - 1);
#pragma unroll
    for (int ct = 0; ct < 4; ++ct) {
#pragma unroll
      for (int r = 0; r < 4; ++r) {
        float s = fmaf(TWOC, sc[ct][r], -k2v[ct]);
        if (diag) {
          const int gi = w * 16 + quad * 4 + r;
          const int gj = ct * 16 + l15;
          s = (gj <= gi) ? s : -1e30f;
        }
        sc[ct][r] = s;
      }
    }

    float al[4];
#pragma unroll
    for (int r = 0; r < 4; ++r) {
      float rm = fmaxf(fmaxf(sc[0][r], sc[1][r]), fmaxf(sc[2][r], sc[3][r]));
      rm = fmaxf(rm, __shfl_xor(rm, 1));
      rm = fmaxf(rm, __shfl_xor(rm, 2));
      rm = fmaxf(rm, __shfl_xor(rm, 4));
      rm = fmaxf(rm, __shfl_xor(rm, 8));
      const float mn = fmaxf(mrow[r], rm);
      al[r] = __expf(mrow[r] - mn);
      mrow[r] = mn;
      float ps = 0.f;
#pragma unroll
      for (int ct = 0; ct < 4; ++ct) {
        const float p = __expf(sc[ct][r] - mn);
        sc[ct][r] = p;
        ps += p;
      }
      ps += __shfl_xor(ps, 1);
      ps += __shfl_xor(ps, 2);
      ps += __shfl_xor(ps, 4);
      ps += __shfl_xor(ps, 8);
      lrow[r] = lrow[r] * al[r] + ps;
    }
#pragma unroll
    for (int nt = 0; nt < 8; ++nt)
#pragma unroll
      for (int r = 0; r < 4; ++r) o[nt][r] *= al[r];

#pragma unroll
    for (int ct = 0; ct < 4; ++ct)
#pragma unroll
      for (int r = 0; r < 4; ++r)
        Ps[w][(quad * 4 + r) * 72 + ct * 16 + l15] = f2b(sc[ct][r]);

#pragma unroll
    for (int kt2 = 0; kt2 < 2; ++kt2) {
      V16 pa;
      pa.u = *(const uint4*)&Ps[w][l15 * 72 + kt2 * 32 + quad * 8];
#pragma unroll
      for (int nt = 0; nt < 8; ++nt) {
        V16 vb;
        const int dd = nt * 16 + l15;
        const int gs = (kt2 * 4 + quad) ^ nt;
        vb.u = *(const uint4*)&VTs[dd * 72 + gs * 8];
        o[nt] = mfma16(pa.b, vb.b, o[nt]);
      }
    }
  }

  float invl[4];
#pragma unroll
  for (int r = 0; r < 4; ++r) invl[r] = 1.f / lrow[r];
#pragma unroll
  for (int nt = 0; nt < 8; ++nt) {
#pragma unroll
    for (int r = 0; r < 4; ++r) {
      const int gi = i0 + w * 16 + quad * 4 + r;
      ctx[(size_t)gi * Cw + h * 128 + nt * 16 + l15] = f2b(o[nt][r] * invl[r]);
    }
  }
}

// ---------------- driver ----------------
extern "C" void kernel_launch(void* const* d_in, const int* in_sizes, int n_in,
                              void* d_out, int out_size, void* d_ws, size_t ws_size,
                              hipStream_t stream) {
  (void)in_sizes; (void)n_in; (void)out_size; (void)ws_size;
  const float* hid  = (const float*)d_in[0];
  const float* cosb = (const float*)d_in[1];
  const float* sinb = (const float*)d_in[2];
  // d_in[3] attention_mask: exactly causal -> applied analytically
  const float* ln1w = (const float*)d_in[4];
  const float* wq   = (const float*)d_in[5];
  const float* wk   = (const float*)d_in[6];
  const float* wv   = (const float*)d_in[7];
  const float* wo   = (const float*)d_in[8];
  const float* ln2w = (const float*)d_in[9];
  const float* wg   = (const float*)d_in[10];
  const float* wu   = (const float*)d_in[11];
  const float* wd   = (const float*)d_in[12];
  float* outp = (float*)d_out;

  const size_t SC = (size_t)2048 * 2048;       // 4.19M
  const size_t FC = (size_t)8192 * 2048;       // 16.78M
  unsigned short* p = (unsigned short*)d_ws;
  unsigned short* wqb = p;  p += SC;
  unsigned short* wkb = p;  p += SC;
  unsigned short* wvb = p;  p += SC;
  unsigned short* wob = p;  p += SC;
  unsigned short* wgb = p;  p += FC;
  unsigned short* wub = p;  p += FC;
  unsigned short* wdb = p;  p += FC;
  unsigned short* xn  = p;  p += SC;           // reused as yn
  unsigned short* qb  = p;  p += SC;
  unsigned short* kb  = p;  p += SC;
  unsigned short* vb  = p;  p += SC;
  unsigned short* ctxb = p; p += SC;
  float* hf = (float*)p;   p += 2 * SC;        // f32 h = hidden + attn_out
  float* k2cb = (float*)p;                     // [H][S] = k^2 * c
  unsigned short* yn = xn;                     // xn dead after QKV
  unsigned short* gb = qb;                     // qb..ctxb (4*SC) dead after wo-proj
  float* qpart = (float*)wqb;                  // wqb..wob (4*SC shorts = 2*SC floats):
                                               // dead after wo-proj -> down split-K partials

  // 0. all weights f32 -> bf16 (one launch; dst regions contiguous)
  cvt_all<<<65536, 256, 0, stream>>>(wq, wk, wv, wo, wg, wu, wd, wqb);

  // 1. input RMSNorm
  rms_k<<<2048, 256, 0, stream>>>(hid, ln1w, xn);
  // 2. fused QKV projection (gridDim.z selects weight/output)
  gemm_nt<0, 4><<<dim3(16, 16, 3), 256, 0, stream>>>(xn, wqb, wkb, wvb, qb, kb, vb,
                                                     nullptr, nullptr, 2048, 2048, 2048);
  // 3. RoPE in-place on q,k + k^2*c precompute
  rope_qk<<<8192, 256, 0, stream>>>(qb, kb, cosb, sinb, k2cb);
  // 4. W2 attention -> ctx
  flash_w2<<<dim3(32, 16), 256, 0, stream>>>(qb, kb, vb, k2cb, ctxb);
  // 5. output projection + residual -> h (f32)
  gemm_nt<1, 2><<<dim3(16, 32, 1), 256, 0, stream>>>(ctxb, wob, wob, wob,
                                                     nullptr, nullptr, nullptr,
                                                     hid, hf, 2048, 2048, 2048);
  // 6. post-attn RMSNorm
  rms_k<<<2048, 256, 0, stream>>>(hf, ln2w, yn);
  // 7+8. fused gate+up GEMM, epilogue silu(g)*u -> gb
  gemm_nt2<<<dim3(64, 16), 256, 0, stream>>>(yn, wgb, wub, gb, 8192, 2048);
  // 9. down GEMM, split-K=2 -> partials over dead wq..wo bf16 region
  gemm_nt<3, 4><<<dim3(16, 16, 2), 256, 0, stream>>>(gb, wdb, wdb, wdb,
                                                     nullptr, nullptr, nullptr,
                                                     nullptr, qpart, 2048, 4096, 8192);
  // 10. combine: out = hf + partial0 + partial1
  comb_k<<<4096, 256, 0, stream>>>(qpart, qpart + SC, hf, outp);
}